// Round 16
// baseline (479.931 us; speedup 1.0000x reference)
//
#include <hip/hip_runtime.h>
#include <stdint.h>

#define QN    300
#define WN    10
#define CD    640
#define IJ    196
#define MROWS 1960              // WN*IJ
#define NTOT  58800             // QN*IJ
#define OUTQ  384160            // MROWS*IJ
#define EPSV  1e-8f

#define BM    256
#define BN    256
#define BK    64
#define BUFE  ((BM + BN) * BK)         // 32768 ushorts = 64 KB per buffer
#define NTK   (CD / BK)                // 10 K-tiles

#define MT_TILES 8                     // m tiles of 256 (pad 2048)
#define NT_TILES 230                   // n tiles of 256 (pad 58880)
#define NWG      (MT_TILES * NT_TILES) // 1840 tiles
#define CPX      (NWG / 8)             // 230
#define PBLK     256                   // persistent blocks (1/CU)

typedef __attribute__((ext_vector_type(8))) short bf16x8;
typedef __attribute__((ext_vector_type(4))) float f32x4;

__device__ __forceinline__ unsigned short f2bf(float f) {
    uint32_t u = __float_as_uint(f);
    u += 0x7FFFu + ((u >> 16) & 1u);   // RNE
    return (unsigned short)(u >> 16);
}

__device__ __forceinline__ void gload16(const void* g, void* l) {
    __builtin_amdgcn_global_load_lds(
        (const __attribute__((address_space(1))) void*)g,
        (__attribute__((address_space(3))) void*)l,
        16, 0, 0);
}

// ---------------------------------------------------------------------------
// Combined pre-pass (ONE launch, round-10 verified): X[b][640][196] fp32 ->
// XT[row][640] bf16 (k contiguous) with the 3-bit swizzle baked per 16B unit
// within each 8-unit (64-elem) K-group: stored_unit = (u&8)|((u&7)^(row&7)),
// plus fp32 norms.  grid = (4, 310): y<300 -> query, else proto.
// ---------------------------------------------------------------------------
__global__ __launch_bounds__(256)
void prep_all(const float* __restrict__ proto, const float* __restrict__ query,
              uint4* __restrict__ pT, uint4* __restrict__ qT,
              float* __restrict__ pn, float* __restrict__ qn)
{
    __shared__ float T[128][65];
    __shared__ float ssL[64][17];

    const int bi = blockIdx.y;
    const bool isQ = (bi < QN);
    const int b  = isQ ? bi : bi - QN;
    const float* Xb = (isQ ? query : proto) + (size_t)b * (CD * IJ);
    uint4* XT   = isQ ? qT : pT;
    float* nrm  = isQ ? qn : pn;
    const int rowbase = b * IJ;

    const int i0 = blockIdx.x * 64;
    const int t  = threadIdx.x;

    const int cg = t >> 4;
    const int i4 = (t & 15) * 4;
    const int iv = i0 + i4;
    const bool liv = (iv <= IJ - 4);

    const int u   = t & 15;
    const int ilb = (t >> 4) * 4;

    float ss[4] = {0.f, 0.f, 0.f, 0.f};

    for (int cc = 0; cc < CD / 128; ++cc) {
        #pragma unroll
        for (int pass = 0; pass < 8; ++pass) {
            int cl = pass * 16 + cg;
            int c  = cc * 128 + cl;
            float4 v = make_float4(0.f, 0.f, 0.f, 0.f);
            if (liv) v = *(const float4*)&Xb[(size_t)c * IJ + iv];
            T[cl][i4 + 0] = v.x; T[cl][i4 + 1] = v.y;
            T[cl][i4 + 2] = v.z; T[cl][i4 + 3] = v.w;
        }
        __syncthreads();
        #pragma unroll
        for (int j = 0; j < 4; ++j) {
            int il = ilb + j;
            float v[8];
            #pragma unroll
            for (int r = 0; r < 8; ++r) { v[r] = T[u * 8 + r][il]; ss[j] += v[r] * v[r]; }
            int ig = i0 + il;
            if (ig < IJ) {
                union { unsigned short s[8]; uint4 q; } pk;
                #pragma unroll
                for (int r = 0; r < 8; ++r) pk.s[r] = f2bf(v[r]);
                int rowg = rowbase + ig;
                int us = (u & 8) | ((u & 7) ^ (rowg & 7));
                XT[(size_t)rowg * (CD / 8) + cc * 16 + us] = pk.q;
            }
        }
        __syncthreads();
    }

    #pragma unroll
    for (int j = 0; j < 4; ++j) ssL[ilb + j][u] = ss[j];
    __syncthreads();
    if (t < 64) {
        int ig = i0 + t;
        if (ig < IJ) {
            float s = 0.f;
            #pragma unroll
            for (int k = 0; k < 16; ++k) s += ssL[t][k];
            nrm[rowbase + ig] = sqrtf(s);
        }
    }
}

// ---------------------------------------------------------------------------
// GEMM -- PERSISTENT BLOCKS over the round-10 verified 8-phase loop.
// C[m][n] = sum_c AT[m][c]*BT[n][c].  256x256 tile, BK=64, 8 waves (2M x 4N),
// per-wave 128x64 (acc[8][4]).  Grid = 256 (1 block/CU, co-resident); block
// b processes tiles v = b, b+256, ... (v&7 const -> XCD chunk stable; mt
// const -> A panel L2-resident per block).  The loop body, phases, counted
// VMC(2) gates and hazards are byte-identical to round 10; the only change:
// in the LAST (peeled) iteration of each tile, the staging pointers are
// reset before P4/P5/P6/P7 so the tail stages (garbage in R10) fetch the
// NEXT tile's K0 (P4: A0, P5: B0, P6: A1, P7: B1) and K1-A0 (P8).  After
// the peeled P8's VMC(2)+BAR the pipeline state (buf0 = next K0 landed,
// next K1-A0 in flight, 2 outstanding) EQUALS the old prologue exit state,
// so the next tile's K-loop starts with zero fill.  Epilogue (acc-only, no
// LDS) runs between tiles; its stores drain under the next tile's P1-P3;
// the next VMC(2) gate simply also waits them out (counted, correct).
// ---------------------------------------------------------------------------
__global__ __launch_bounds__(512, 2)
void gemm_kernel(const uint4* __restrict__ AT, const uint4* __restrict__ BT,
                 const float* __restrict__ pn, const float* __restrict__ qn,
                 float* __restrict__ out)
{
    __shared__ unsigned short lds[2 * BUFE];   // 128 KB

    const int b   = blockIdx.x;                // 0..255
    const int cnt = (b < NWG - 7 * PBLK) ? 8 : 7;   // 1840 = 7*256 + 48

    const int t  = threadIdx.x;
    const int w  = t >> 6, l = t & 63;
    const int fr = l & 15, fq = l >> 4;
    const int wm0 = (w >> 2) * 128;   // 2 M-waves
    const int wn0 = (w & 3) * 64;     // 4 N-waves
    const int lr = l >> 3, lu = l & 7;

    // wave-uniform LDS element offsets (HW adds lane*16B) -- tile-independent
    const int la00 = (  0 + w * 8) * 64;
    const int la01 = ( 64 + w * 8) * 64;
    const int la10 = (128 + w * 8) * 64;
    const int la11 = (192 + w * 8) * 64;
    const int lb00 = BM * 64 + (  0 + w * 8) * 64;
    const int lb01 = BM * 64 + ( 64 + w * 8) * 64;
    const int lb10 = BM * 64 + (128 + w * 8) * 64;
    const int lb11 = BM * 64 + (192 + w * 8) * 64;

    // fragment read bases + swizzle keys -- tile-independent
    const int fqS0 = fq << 3;
    const int fqS1 = (fq + 4) << 3;
    int baA[8], kyA[8], baB[4], kyB[4];
    #pragma unroll
    for (int i = 0; i < 8; ++i) {
        int rowa = wm0 + i * 16 + fr;
        baA[i] = rowa * 64;  kyA[i] = (rowa & 7) << 3;
    }
    #pragma unroll
    for (int i = 0; i < 4; ++i) {
        int rowb = wn0 + i * 16 + fr;
        baB[i] = BM * 64 + rowb * 64;  kyB[i] = (rowb & 7) << 3;
    }

#define SETPA(P, RB) { int r_ = (RB) + w * 8 + lr;                        \
    if (r_ > MROWS - 1) r_ = MROWS - 1;                                   \
    P = AT + (size_t)r_ * 80 + lu; }
#define SETPB(P, RB) { int r_ = (RB) + w * 8 + lr;                        \
    if (r_ > NTOT - 1) r_ = NTOT - 1;                                     \
    P = BT + (size_t)r_ * 80 + lu; }

    // ---- first tile
    int v   = b;
    int szv = (v & 7) * CPX + (v >> 3);
    int m0  = (szv & (MT_TILES - 1)) * BM;
    int n0  = (szv >> 3) * BN;

    const uint4 *ga00, *ga01, *ga10, *ga11, *gb00, *gb01, *gb10, *gb11;
    SETPA(ga00, m0 +   0); SETPA(ga01, m0 +  64);
    SETPA(ga10, m0 + 128); SETPA(ga11, m0 + 192);
    SETPB(gb00, n0 +   0); SETPB(gb01, n0 +  64);
    SETPB(gb10, n0 + 128); SETPB(gb11, n0 + 192);

    f32x4 acc[8][4];

#define ST2(PA, PB, LA, LB)                                               \
    gload16(PA, (char*)&lds[(LA)]); PA += 8;                              \
    gload16(PB, (char*)&lds[(LB)]); PB += 8;

#define RD_A(OC, G)                                                       \
    _Pragma("unroll")                                                     \
    for (int mm = 0; mm < 4; ++mm) {                                      \
        af[mm]   = *(const bf16x8*)&lds[(OC) + baA[(G)+mm]                \
                                        + (fqS0 ^ kyA[(G)+mm])];          \
        af[4+mm] = *(const bf16x8*)&lds[(OC) + baA[(G)+mm]                \
                                        + (fqS1 ^ kyA[(G)+mm])];          \
    }
#define RD_B(BV, OC, G)                                                   \
    _Pragma("unroll")                                                     \
    for (int nn = 0; nn < 2; ++nn) {                                      \
        BV[nn]   = *(const bf16x8*)&lds[(OC) + baB[(G)+nn]                \
                                        + (fqS0 ^ kyB[(G)+nn])];          \
        BV[2+nn] = *(const bf16x8*)&lds[(OC) + baB[(G)+nn]                \
                                        + (fqS1 ^ kyB[(G)+nn])];          \
    }
#define MF(MB, NB, BV)                                                    \
    _Pragma("unroll")                                                     \
    for (int ks = 0; ks < 2; ++ks)                                        \
        _Pragma("unroll")                                                 \
        for (int mm = 0; mm < 4; ++mm)                                    \
            _Pragma("unroll")                                             \
            for (int nn = 0; nn < 2; ++nn)                                \
                acc[(MB)+mm][(NB)+nn] =                                   \
                    __builtin_amdgcn_mfma_f32_16x16x32_bf16(              \
                        BV[ks*2+nn], af[ks*4+mm],                         \
                        acc[(MB)+mm][(NB)+nn], 0, 0, 0);

#define BAR    __builtin_amdgcn_s_barrier()
#define LGKM0  do { asm volatile("s_waitcnt lgkmcnt(0)" ::: "memory");    \
                    __builtin_amdgcn_sched_barrier(0); } while (0)
#define VMC(N) asm volatile("s_waitcnt vmcnt(" #N ")" ::: "memory")
#define PRIO1  __builtin_amdgcn_s_setprio(1)
#define PRIO0  __builtin_amdgcn_s_setprio(0)

// 8-phase / 2-K-tile iteration; R4..R7 are pointer-reset hooks (empty for
// normal iterations, next-tile resets for the peeled last iteration).
#define ITER(R4, R5, R6, R7)                                              \
  { bf16x8 af[8], b0[4], b1[4];                                           \
    /* P1 */                                                              \
    RD_A(0, 0); RD_B(b0, 0, 0);                                           \
    ST2(gb00, gb01, BUFE + lb00, BUFE + lb01);                            \
    BAR; LGKM0;                                                           \
    PRIO1; MF(0, 0, b0); PRIO0;                                           \
    /* P2 */                                                              \
    RD_B(b1, 0, 2);                                                       \
    ST2(ga10, ga11, BUFE + la10, BUFE + la11);                            \
    BAR; LGKM0;                                                           \
    PRIO1; MF(0, 2, b1); PRIO0;                                           \
    /* P3 */                                                              \
    RD_A(0, 4);                                                           \
    ST2(gb10, gb11, BUFE + lb10, BUFE + lb11);                            \
    BAR; LGKM0;                                                           \
    PRIO1; MF(4, 2, b1); PRIO0;                                           \
    /* P4 (gate) */                                                       \
    R4;                                                                   \
    ST2(ga00, ga01, la00, la01);                                          \
    PRIO1; MF(4, 0, b0); PRIO0;                                           \
    VMC(2); BAR;                                                          \
    /* P5 */                                                              \
    RD_A(BUFE, 0); RD_B(b0, BUFE, 0);                                     \
    R5;                                                                   \
    ST2(gb00, gb01, lb00, lb01);                                          \
    BAR; LGKM0;                                                           \
    PRIO1; MF(0, 0, b0); PRIO0;                                           \
    /* P6 */                                                              \
    RD_B(b1, BUFE, 2);                                                    \
    R6;                                                                   \
    ST2(ga10, ga11, la10, la11);                                          \
    BAR; LGKM0;                                                           \
    PRIO1; MF(0, 2, b1); PRIO0;                                           \
    /* P7 */                                                              \
    RD_A(BUFE, 4);                                                        \
    R7;                                                                   \
    ST2(gb10, gb11, lb10, lb11);                                          \
    BAR; LGKM0;                                                           \
    PRIO1; MF(4, 2, b1); PRIO0;                                           \
    /* P8 (gate) */                                                       \
    ST2(ga00, ga01, BUFE + la00, BUFE + la01);                            \
    PRIO1; MF(4, 0, b0); PRIO0;                                           \
    VMC(2); BAR; }

#define NOP_    do {} while (0)
#define RST_A0  do { SETPA(ga00, m0n +   0); SETPA(ga01, m0n +  64); } while (0)
#define RST_B0  do { SETPB(gb00, n0n +   0); SETPB(gb01, n0n +  64); } while (0)
#define RST_A1  do { SETPA(ga10, m0n + 128); SETPA(ga11, m0n + 192); } while (0)
#define RST_B1  do { SETPB(gb10, n0n + 128); SETPB(gb11, n0n + 192); } while (0)

    // ---- prologue (once per block): tile-v K0 fully -> buf0; K1-A0 -> buf1.
    ST2(ga00, ga01, la00, la01);               // K0 A0
    ST2(gb00, gb01, lb00, lb01);               // K0 B0
    ST2(ga10, ga11, la10, la11);               // K0 A1
    ST2(gb10, gb11, lb10, lb11);               // K0 B1
    ST2(ga00, ga01, BUFE + la00, BUFE + la01); // K1 A0
    VMC(2); BAR;

    for (int k = 0; k < cnt; ++k) {
        #pragma unroll
        for (int a = 0; a < 8; ++a)
            #pragma unroll
            for (int bb = 0; bb < 4; ++bb)
                acc[a][bb] = (f32x4){0.f, 0.f, 0.f, 0.f};

        // 4 normal iterations (K-tiles 0..7)
        for (int i5 = 0; i5 < 4; ++i5) {
            ITER(NOP_, NOP_, NOP_, NOP_)
        }

        // peeled last iteration (K-tiles 8,9): tail stages fetch next tile
        int vn  = (k + 1 < cnt) ? v + PBLK : v;
        int szn = (vn & 7) * CPX + (vn >> 3);
        int m0n = (szn & (MT_TILES - 1)) * BM;
        int n0n = (szn >> 3) * BN;
        ITER(RST_A0, RST_B0, RST_A1, RST_B1)

        // ---- epilogue for tile (m0, n0): acc-only, no LDS; stores drain
        // under the next tile's first phases.
        {
            float4 rqv4[4];
            int    nok[4];
            size_t ob[4];
            #pragma unroll
            for (int tn = 0; tn < 4; ++tn) {
                int n = n0 + wn0 + tn * 16 + fq * 4;
                nok[tn] = (n < NTOT);
                int nc = nok[tn] ? n : NTOT - 4;
                int q  = nc / IJ;
                int j  = nc - q * IJ;
                rqv4[tn] = *(const float4*)&qn[nc];
                ob[tn] = (size_t)q * OUTQ + j;
            }
            #pragma unroll
            for (int tm = 0; tm < 8; ++tm) {
                int m = m0 + wm0 + tm * 16 + fr;
                if (m < MROWS) {
                    float rp = pn[m];
                    #pragma unroll
                    for (int tn = 0; tn < 4; ++tn) {
                        if (nok[tn]) {
                            f32x4 a = acc[tm][tn];
                            float4 o;
                            o.x = a[0] * __builtin_amdgcn_rcpf(fmaxf(rp * rqv4[tn].x, EPSV));
                            o.y = a[1] * __builtin_amdgcn_rcpf(fmaxf(rp * rqv4[tn].y, EPSV));
                            o.z = a[2] * __builtin_amdgcn_rcpf(fmaxf(rp * rqv4[tn].z, EPSV));
                            o.w = a[3] * __builtin_amdgcn_rcpf(fmaxf(rp * rqv4[tn].w, EPSV));
                            *(float4*)&out[ob[tn] + (size_t)m * IJ] = o;
                        }
                    }
                }
            }
        }

        v = vn; m0 = m0n; n0 = n0n;
    }

    VMC(0);   // drain the final tile's redundant prefetch before endpgm

#undef ITER
#undef NOP_
#undef RST_A0
#undef RST_B0
#undef RST_A1
#undef RST_B1
#undef ST2
#undef RD_A
#undef RD_B
#undef MF
#undef BAR
#undef LGKM0
#undef VMC
#undef PRIO1
#undef PRIO0
#undef SETPA
#undef SETPB
}

// ---------------------------------------------------------------------------
// Fallback (round-1 kernel, known-passing) if ws_size is insufficient.
// ---------------------------------------------------------------------------
#define BMF 128
#define BNF 224
#define LPAD 40
__global__ __launch_bounds__(512, 4)
void sim_fallback(const float* __restrict__ proto,
                  const float* __restrict__ query,
                  float* __restrict__ out)
{
    __shared__ unsigned short As[BMF][LPAD];
    __shared__ unsigned short Bs[BNF][LPAD];
    __shared__ float redA[4][BMF];
    __shared__ float redB[2][BNF];
    __shared__ float rpS[BMF];
    __shared__ float rqS[BNF];

    const int tid = threadIdx.x;
    const int m0  = blockIdx.x * BMF;
    const int q   = blockIdx.y;

    const int mA  = tid & (BMF - 1);
    const int krA = tid >> 7;
    const int wiA = m0 + mA;
    const bool va = (wiA < MROWS);
    const int wA  = va ? (wiA / IJ) : 0;
    const int iA  = va ? (wiA - wA * IJ) : 0;
    const float* pA = proto + wA * (CD * IJ) + iA;

    const bool tb  = (tid < 448);
    const int jB   = tb ? (tid % BNF) : 0;
    const int krB  = tb ? (tid / BNF) : 0;
    const bool vb  = tb && (jB < IJ);
    const float* qB = query + q * (CD * IJ) + jB;

    float ssA = 0.f, ssB = 0.f;

    const int wv   = tid >> 6;
    const int lane = tid & 63;
    const int wm0  = (wv >> 1) * 32;
    const int wn0  = (wv & 1) * 112;
    const int fr   = lane & 15;
    const int fq   = lane >> 4;

    f32x4 acc[2][7];
    #pragma unroll
    for (int a = 0; a < 2; a++)
        #pragma unroll
        for (int b = 0; b < 7; b++)
            acc[a][b] = (f32x4){0.f, 0.f, 0.f, 0.f};

    for (int it = 0; it < CD / 32; ++it) {
        const int c0 = it * 32;
        {
            float v[8];
            #pragma unroll
            for (int e = 0; e < 8; e++) {
                int c = c0 + krA * 8 + e;
                v[e] = va ? pA[c * IJ] : 0.f;
            }
            #pragma unroll
            for (int e = 0; e < 8; e++) ssA += v[e] * v[e];
            union { unsigned short s[8]; uint4 u; } pk;
            #pragma unroll
            for (int e = 0; e < 8; e++) pk.s[e] = f2bf(v[e]);
            *(uint4*)&As[mA][krA * 8] = pk.u;
        }
        if (tb) {
            #pragma unroll
            for (int h = 0; h < 2; ++h) {
                float v[8];
                #pragma unroll
                for (int e = 0; e < 8; e++) {
                    int c = c0 + krB * 16 + h * 8 + e;
                    v[e] = vb ? qB[c * IJ] : 0.f;
                }
                #pragma unroll
                for (int e = 0; e < 8; e++) ssB += v[e] * v[e];
                union { unsigned short s[8]; uint4 u; } pk;
                #pragma unroll
                for (int e = 0; e < 8; e++) pk.s[e] = f2bf(v[e]);
                *(uint4*)&Bs[jB][krB * 16 + h * 8] = pk.u;
            }
        }
        __syncthreads();
        bf16x8 af[2], bfv[7];
        #pragma unroll
        for (int tm = 0; tm < 2; tm++)
            af[tm] = *(const bf16x8*)&As[wm0 + tm * 16 + fr][fq * 8];
        #pragma unroll
        for (int tn = 0; tn < 7; tn++)
            bfv[tn] = *(const bf16x8*)&Bs[wn0 + tn * 16 + fr][fq * 8];
        #pragma unroll
        for (int tm = 0; tm < 2; tm++)
            #pragma unroll
            for (int tn = 0; tn < 7; tn++)
                acc[tm][tn] = __builtin_amdgcn_mfma_f32_16x16x32_bf16(
                    af[tm], bfv[tn], acc[tm][tn], 0, 0, 0);
        __syncthreads();
    }

    redA[krA][mA] = ssA;
    if (tb) redB[krB][jB] = ssB;
    __syncthreads();
    if (tid < BMF) {
        rpS[tid] = sqrtf(redA[0][tid] + redA[1][tid] + redA[2][tid] + redA[3][tid]);
    } else if (tid >= 256 && tid < 256 + BNF) {
        int j = tid - 256;
        rqS[j] = sqrtf(redB[0][j] + redB[1][j]);
    }
    __syncthreads();

    #pragma unroll
    for (int tm = 0; tm < 2; tm++) {
        #pragma unroll
        for (int tn = 0; tn < 7; tn++) {
            #pragma unroll
            for (int r = 0; r < 4; r++) {
                int rl = wm0 + tm * 16 + fq * 4 + r;
                int cl = wn0 + tn * 16 + fr;
                int wi = m0 + rl;
                if (wi < MROWS && cl < IJ) {
                    float denom = fmaxf(rpS[rl] * rqS[cl], 1e-8f);
                    out[(size_t)(q * MROWS + wi) * IJ + cl] = acc[tm][tn][r] / denom;
                }
            }
        }
    }
}

// ---------------------------------------------------------------------------
extern "C" void kernel_launch(void* const* d_in, const int* in_sizes, int n_in,
                              void* d_out, int out_size, void* d_ws, size_t ws_size,
                              hipStream_t stream) {
    const float* proto = (const float*)d_in[0];
    const float* query = (const float*)d_in[1];
    float* out = (float*)d_out;

    // workspace layout
    const size_t off_pT = 0;                       // 1960*640*2 = 2,508,800
    const size_t off_qT = 2508800;                 // 58800*640*2 = 75,264,000
    const size_t off_pn = 77772800;                // 1960*4
    const size_t off_qn = 77780736;                // 58800*4
    const size_t need   = 78015936;

    if (ws_size < need) {
        dim3 grid((MROWS + BMF - 1) / BMF, QN);
        sim_fallback<<<grid, 512, 0, stream>>>(proto, query, out);
        return;
    }

    char* ws = (char*)d_ws;
    uint4* pT = (uint4*)(ws + off_pT);
    uint4* qT = (uint4*)(ws + off_qT);
    float* pn = (float*)(ws + off_pn);
    float* qn = (float*)(ws + off_qn);

    prep_all<<<dim3(4, QN + WN), 256, 0, stream>>>(proto, query, pT, qT, pn, qn);

    gemm_kernel<<<dim3(PBLK), 512, 0, stream>>>(pT, qT, pn, qn, out);
}